// Round 6
// baseline (115.578 us; speedup 1.0000x reference)
//
#include <hip/hip_runtime.h>

#define RADIUS 5
#define WIN 9
#define BB 4
#define KK 4
#define HH 224
#define WW 224
#define HW (HH * WW)
#define PD 234                 // HH + 2*RADIUS
#define PAREA (PD * PD)        // 54756
#define NBUCKET 64
#define PARTIAL_FLOATS (NBUCKET * BB * 8)   // 2048 floats = 8 KB

// ---- main tiling: 1 wave per block, 32 pixels per block (2 lanes per pixel) ----
#define SEGPIX 32
#define SEGS_PER_ROW 7                      // 224/32
#define SEGS_PER_B (HH * SEGS_PER_ROW)      // 1568
#define NBLK (BB * SEGS_PER_B)              // 6272
#define WSEG_FLOATS (SEGPIX * 81)           // 2592
#define WSEG_BYTES (WSEG_FLOATS * 4)        // 10368 B  -> ~15 blocks/CU
#define WSEG_FULL 10                        // 10 x 1024B DMA ops
#define WSEG_REM_LANES 8                    // tail: 128 B (8 lanes x 16B)

// d_ws layout (floats):
//   [0, 2048)                      : partial buckets [bucket][b][8] (0..3 A_k, 4..7 V_k)
//   [2048, 2048 + B*PAREA*4)       : padded seg P[b][r][c][k], float4 per (r,c)

// ---------- pre-pass: zero partials + seg [B,K,H,W] -> zero-padded [B,PD,PD,K] ----------
__global__ __launch_bounds__(256) void ncuts_pad(
    const float* __restrict__ seg, float4* __restrict__ pseg, float* __restrict__ zr)
{
    const int tid = blockIdx.x * 256 + threadIdx.x;
    if (tid < PARTIAL_FLOATS) zr[tid] = 0.f;        // partial buckets
    if (tid >= BB * PAREA) return;
    const int b  = tid / PAREA;
    const int rc = tid - b * PAREA;
    const int r  = rc / PD;
    const int c  = rc - r * PD;
    const int hh = r - RADIUS;
    const int ww = c - RADIUS;
    float4 v = {0.f, 0.f, 0.f, 0.f};
    if (hh >= 0 && hh < HH && ww >= 0 && ww < WW) {
        const float* sb = seg + (size_t)b * KK * HW + hh * WW + ww;
        v.x = sb[0 * HW];
        v.y = sb[1 * HW];
        v.z = sb[2 * HW];
        v.w = sb[3 * HW];
    }
    pseg[tid] = v;
}

// ---------- main: 1 wave = 32 pixels, 2 lanes/pixel (n-parity split), LDS-DMA weights ----------
__global__ __launch_bounds__(64) void ncuts_main(
    const float* __restrict__ weight,
    const float4* __restrict__ pseg,
    float* __restrict__ partial)
{
    __shared__ float wlds[WSEG_FLOATS];   // 10368 B -> ~15 resident waves/CU

    const int lane = threadIdx.x;          // 0..63
    const int blk  = blockIdx.x;
    const int b    = blk / SEGS_PER_B;     // uniform per block (1568 = 7*224 per image)
    const int sb   = blk - b * SEGS_PER_B;
    const int h    = sb / SEGS_PER_ROW;
    const int w0   = (sb - h * SEGS_PER_ROW) * SEGPIX;
    const int q    = lane >> 1;            // pixel 0..31 within segment
    const int z    = lane & 1;             // window-column parity

    // --- stage this block's 32*81 weights into LDS (contiguous, lane-linear DMA) ---
    const float4* wsrc = (const float4*)(weight + (size_t)blk * WSEG_FLOATS);
    float4* ldsb = (float4*)wlds;
    #pragma unroll
    for (int j = 0; j < WSEG_FULL; ++j)
        __builtin_amdgcn_global_load_lds(
            (__attribute__((address_space(1))) void*)(wsrc + j * 64 + lane),
            (__attribute__((address_space(3))) void*)(ldsb + j * 64),
            16, 0, 0);
    if (lane < WSEG_REM_LANES)
        __builtin_amdgcn_global_load_lds(
            (__attribute__((address_space(1))) void*)(wsrc + WSEG_FULL * 64 + lane),
            (__attribute__((address_space(3))) void*)(ldsb + WSEG_FULL * 64),
            16, 0, 0);

    const float4* p4 = pseg + (size_t)b * PAREA;
    // center load issues before the drain -> latency hidden under DMA
    const float4 t = p4[(h + RADIUS) * PD + (w0 + q + RADIUS)];

    __syncthreads();   // vmcnt(0) drain; cross-wave TLP (~15 waves/CU) hides it

    const float* wl = wlds + q * 81;

    float a0 = 0.f, a1 = 0.f, a2 = 0.f, a3 = 0.f, ws = 0.f;

    #pragma unroll
    for (int m = 0; m < WIN; ++m) {
        const int rowbase = (h + m) * PD + w0 + q;
        // n = 2j + z for j=0..3 (all lanes), plus n=8 for even lanes only
        #pragma unroll
        for (int j = 0; j < 4; ++j) {
            const int n = 2 * j + z;
            const float  wv = wl[m * WIN + n];     // LDS, ~2 lanes/bank
            const float4 sv = p4[rowbase + n];     // global, coalesced ~33 float4/wave
            a0 = fmaf(wv, sv.x, a0);
            a1 = fmaf(wv, sv.y, a1);
            a2 = fmaf(wv, sv.z, a2);
            a3 = fmaf(wv, sv.w, a3);
            ws += wv;
        }
        if (z == 0) {
            const float  wv = wl[m * WIN + 8];
            const float4 sv = p4[rowbase + 8];
            a0 = fmaf(wv, sv.x, a0);
            a1 = fmaf(wv, sv.y, a1);
            a2 = fmaf(wv, sv.z, a2);
            a3 = fmaf(wv, sv.w, a3);
            ws += wv;
        }
    }

    // per-lane partials are linear in w -> multiplying by t and summing pairs is exact
    float vals[8] = { a0 * t.x, a1 * t.y, a2 * t.z, a3 * t.w,
                      ws * t.x, ws * t.y, ws * t.z, ws * t.w };

    // full-wave reduction: merges the lane-pair halves AND the 32 pixels in one tree
    #pragma unroll
    for (int i = 0; i < 8; ++i) {
        float v = vals[i];
        v += __shfl_down(v, 32);
        v += __shfl_down(v, 16);
        v += __shfl_down(v, 8);
        v += __shfl_down(v, 4);
        v += __shfl_down(v, 2);
        v += __shfl_down(v, 1);
        vals[i] = v;
    }

    if (lane == 0) {
        const int bucket = sb & (NBUCKET - 1);
        float* dst = partial + (bucket * BB + b) * 8;
        #pragma unroll
        for (int i = 0; i < 8; ++i)
            atomicAdd(dst + i, vals[i]);
    }
}

// ---------- final: fold buckets, compute loss ----------
__global__ __launch_bounds__(64) void ncuts_final(
    const float* __restrict__ partial, float* __restrict__ out)
{
    __shared__ float sums[32];
    const int t = threadIdx.x;
    if (t < 32) {
        float s = 0.f;
        for (int bucket = 0; bucket < NBUCKET; ++bucket)
            s += partial[bucket * 32 + t];
        sums[t] = s;
    }
    __syncthreads();
    if (t == 0) {
        float total = 0.f;
        for (int b = 0; b < BB; ++b) {
            float assoc = 0.f;
            for (int k = 0; k < KK; ++k) {
                const float A = sums[b * 8 + k];
                const float V = sums[b * 8 + 4 + k];
                assoc += A / V;
            }
            total += (float)KK - assoc;
        }
        out[0] = total;
    }
}

extern "C" void kernel_launch(void* const* d_in, const int* in_sizes, int n_in,
                              void* d_out, int out_size, void* d_ws, size_t ws_size,
                              hipStream_t stream) {
    const float* seg    = (const float*)d_in[0];
    const float* weight = (const float*)d_in[1];
    float* out     = (float*)d_out;
    float* wsf     = (float*)d_ws;
    float* partial = wsf;                               // 2048 floats
    float4* pseg   = (float4*)(wsf + PARTIAL_FLOATS);   // byte offset 8192, 16B aligned

    // pre-pass: zero partials + build padded seg (no separate memset dispatch)
    {
        const int total = BB * PAREA;           // 219024
        const int grid  = (total + 255) / 256;  // 856
        hipLaunchKernelGGL(ncuts_pad, dim3(grid), dim3(256), 0, stream, seg, pseg, wsf);
    }

    // main: 6272 one-wave blocks, 32 pixels each, ~15 resident waves/CU
    hipLaunchKernelGGL(ncuts_main, dim3(NBLK), dim3(64), 0, stream,
                       weight, pseg, partial);

    // final: fold buckets, write loss
    hipLaunchKernelGGL(ncuts_final, dim3(1), dim3(64), 0, stream, partial, out);
}